// Round 13
// baseline (42.732 us; speedup 1.0000x reference)
//
#include <hip/hip_runtime.h>
#include <hip/hip_bf16.h>
#include <math.h>

// BayesianSkipgram: V=100000, E=256, D=128, B=8192, C=10
// v13 = v12 + barrier-free direct idx + pad-free 11-step staging.
//   bsg_h : wave w stages the 11 slot-rows of batch elem b0+w. Indices are
//           loaded per-thread straight from x[] + the contiguous 40B ctx row
//           (wave-uniform -> broadcast), so the gather issues immediately:
//           NO idx_s, NO first barrier. 11 x (1KB-row wave-coalesced load)
//           upfront, 11 ds_writes, ONE barrier, then MFMA.
//           LDS rows 88..95 left unstaged (garbage D rows are discarded).
//   bsg_kl: unchanged from v12.
//   k_cvt : unchanged.
// ws layout (ushort): M_bf [0,32768), U|W_bf [32768,98304), h [98304,+2M).

#define CTXN  10
#define DDIM  128
#define WS_M   0
#define WS_UW  32768
#define WS_H   98304

typedef short bf16x8 __attribute__((ext_vector_type(8)));
typedef float f32x4  __attribute__((ext_vector_type(4)));

__device__ __forceinline__ uint2 cvt4(float4 v) {
    union { __hip_bfloat162 h2; unsigned u; } a, b;
    a.h2 = __float22bfloat162_rn(make_float2(v.x, v.y));
    b.h2 = __float22bfloat162_rn(make_float2(v.z, v.w));
    return make_uint2(a.u, b.u);
}

__device__ __forceinline__ float softplusf(float v) {
    return fmaxf(v, 0.0f) + log1pf(expf(-fabsf(v)));
}

// ---------------- kernel 0: weight fp32 -> bf16 ----------------
__global__ __launch_bounds__(256) void k_cvt(
    const float* __restrict__ M_w, const float* __restrict__ U_w,
    const float* __restrict__ W_w, unsigned short* __restrict__ ws)
{
    int which = blockIdx.x >> 5;                       // 0:M 1:U 2:W
    int i = ((blockIdx.x & 31) << 8) | threadIdx.x;    // float4 idx 0..8191
    const float* src = (which == 0) ? M_w : (which == 1) ? U_w : W_w;
    float4 v = ((const float4*)src)[i];
    *(uint2*)&ws[which * 32768 + i * 4] = cvt4(v);
}

// ---------------- kernel 1: gather + emb@M_w^T + relu-sum -> h ----------------
#define BT1   8
#define ROWSP 96              // LDS rows 0..87 staged (r = c*8+b); 88..95 garbage
#define LP2   264             // A row stride (ushort): 528 B -> 2-way bank alias (free)

__global__ __launch_bounds__(512, 4) void bsg_h(
    const int* __restrict__ x, const int* __restrict__ ctx,
    const float* __restrict__ W_emb, const float* __restrict__ M_b,
    const unsigned short* __restrict__ wsr, unsigned short* __restrict__ hws)
{
    __shared__ __align__(16) unsigned short A_s[ROWSP * LP2];   // 50688 B

    const int tid  = threadIdx.x;
    const int b0   = blockIdx.x * BT1;
    const int w    = tid >> 6;       // wave 0..7 owns d-cols 16w..16w+15
    const int lane = tid & 63;
    const int l15  = lane & 15;
    const int lg   = lane >> 4;

    // ---- direct idx: wave rs stages batch elem b0+rs (rs == wave id) ----
    const int rs = tid >> 6;         // row-within-slot == wave id
    const int qs = tid & 63;         // float4 index in the 1KB row
    const int bm = b0 + rs;

    const int xb = x[bm];            // wave-uniform (broadcast line)
    int ci[10];
    {
        const int2* crow = (const int2*)(ctx + (size_t)bm * CTXN);  // 40B, 8B-aligned
#pragma unroll
        for (int k = 0; k < 5; ++k) { int2 t = crow[k]; ci[2 * k] = t.x; ci[2 * k + 1] = t.y; }
    }

    // ---- single-shot staging: 11 wave-coalesced 1KB-row loads, 1 barrier ----
    const float4* We = (const float4*)W_emb;
    float4 rr[11];
    rr[0] = We[(size_t)xb * 64 + qs];
#pragma unroll
    for (int c = 1; c < 11; ++c) rr[c] = We[(size_t)ci[c - 1] * 64 + qs];
#pragma unroll
    for (int c = 0; c < 11; ++c)
        *(uint2*)&A_s[(8 * c + rs) * LP2 + 4 * qs] = cvt4(rr[c]);
    __syncthreads();   // the only phase-1 barrier

    // ---- MFMA: 4 k-chunks x 6 M-tiles, M-frags from L2-hot bf16 ws ----
    // (tile 5 rows 88..95 are LDS garbage; their D rows are discarded below —
    //  D row i depends only on A row i.)
    const unsigned short* Mb_bf = wsr + WS_M;   // [128][256] bf16
    const int mrow = 16 * w + l15;
    f32x4 acc[6] = {};
#pragma unroll
    for (int ch = 0; ch < 4; ++ch) {
        bf16x8 m0 = *(const bf16x8*)&Mb_bf[mrow * 256 + 64 * ch + 8 * lg];
        bf16x8 m1 = *(const bf16x8*)&Mb_bf[mrow * 256 + 64 * ch + 32 + 8 * lg];
#pragma unroll
        for (int mt = 0; mt < 6; ++mt) {
            bf16x8 a0 = *(const bf16x8*)&A_s[(16 * mt + l15) * LP2 + 64 * ch + 8 * lg];
            bf16x8 a1 = *(const bf16x8*)&A_s[(16 * mt + l15) * LP2 + 64 * ch + 32 + 8 * lg];
            acc[mt] = __builtin_amdgcn_mfma_f32_16x16x32_bf16(a0, m0, acc[mt], 0, 0, 0);
            acc[mt] = __builtin_amdgcn_mfma_f32_16x16x32_bf16(a1, m1, acc[mt], 0, 0, 0);
        }
    }

    // relu-sum: lane row = 16mt+4lg+q; c = row>>3, b = row&7.
    // lg<2 -> even slots (c=2mt), lg>=2 -> odd slots (c=2mt+1; mt=5 -> garbage, excluded).
    const int dg = 16 * w + l15;
    const float mb = M_b[dg];
    float p1[4] = {0, 0, 0, 0}, p2[4] = {0, 0, 0, 0};
#pragma unroll
    for (int mt = 0; mt < 6; ++mt) {
#pragma unroll
        for (int q = 0; q < 4; ++q) {
            float r = fmaxf(acc[mt][q] + mb, 0.0f);
            if (lg < 2) { if (mt == 0) p1[q] = r; else p2[q] += r; }
            else        { if (mt < 5)  p2[q] += r; }
        }
    }
#pragma unroll
    for (int q = 0; q < 4; ++q) {
        float other = __shfl_xor(p2[q], 32);     // pair lg0<->lg2, lg1<->lg3
        if (lg < 2) {
            int b = 4 * lg + q;
            __hip_bfloat16 t1 = __float2bfloat16(10.0f * p1[q]);   // C*relu(Rw)
            __hip_bfloat16 t2 = __float2bfloat16(p2[q] + other);   // sum relu(Rc)
            hws[(size_t)(b0 + b) * 256 + dg]       = *(unsigned short*)&t1;
            hws[(size_t)(b0 + b) * 256 + 128 + dg] = *(unsigned short*)&t2;
        }
    }
}

// ---------------- kernel 2: h @ [U;W]^T + softplus + KL ----------------
#define BT2  16
#define HLP  264

__global__ __launch_bounds__(512, 4) void bsg_kl(
    const int* __restrict__ x, const float* __restrict__ U_b,
    const float* __restrict__ W_b, const float* __restrict__ pmu,
    const float* __restrict__ psg, const unsigned short* __restrict__ wsr,
    float* __restrict__ out)
{
    __shared__ __align__(16) unsigned short H_s[BT2 * HLP];   // 8448 B
    __shared__ float P_s[BT2 * 8];

    const int tid  = threadIdx.x;
    const int b0   = blockIdx.x * BT2;
    const int w    = tid >> 6;       // wave 0..7 owns d-cols 16w..16w+15
    const int lane = tid & 63;
    const int l15  = lane & 15;
    const int lg   = lane >> 4;
    const int d    = 16 * w + l15;

    // prior gathers issued upfront (x[] L2-hot); consumed only in epilogue
    float pm[4], ps[4];
#pragma unroll
    for (int q = 0; q < 4; ++q) {
        int xb = x[b0 + 4 * lg + q];
        pm[q] = pmu[(size_t)xb * DDIM + d];
        ps[q] = psg[(size_t)xb * DDIM + d];
    }

    // h tile copy: 512 threads x 16B = whole [16][256] tile
    const unsigned short* hws = wsr + WS_H;
    {
        int r = tid >> 5, q = tid & 31;
        *(uint4*)&H_s[r * HLP + 8 * q] =
            *(const uint4*)&hws[(size_t)(b0 + r) * 256 + 8 * q];
    }
    __syncthreads();

    const unsigned short* UWb = wsr + WS_UW;    // [256][256]: 0..127=U, 128..255=W
    f32x4 acc2[2] = {};
#pragma unroll
    for (int ks = 0; ks < 8; ++ks) {
        bf16x8 hf = *(const bf16x8*)&H_s[l15 * HLP + 32 * ks + 8 * lg];
        bf16x8 bu = *(const bf16x8*)&UWb[d * 256 + 32 * ks + 8 * lg];
        bf16x8 bw = *(const bf16x8*)&UWb[(128 + d) * 256 + 32 * ks + 8 * lg];
        acc2[0] = __builtin_amdgcn_mfma_f32_16x16x32_bf16(hf, bu, acc2[0], 0, 0, 0);
        acc2[1] = __builtin_amdgcn_mfma_f32_16x16x32_bf16(hf, bw, acc2[1], 0, 0, 0);
    }

    const float ub = U_b[d], wb = W_b[d];
#pragma unroll
    for (int q = 0; q < 4; ++q) {
        int rb = 4 * lg + q;                    // batch row (C/D: row=4lg+q, col=l15)
        float mu = acc2[0][q] + ub;
        float sg = softplusf(acc2[1][q] + wb);
        float dm = mu - pm[q];
        float p  = ps[q] / sg + dm * dm / sg + logf(sg) - logf(ps[q]);
        p += __shfl_xor(p, 1);
        p += __shfl_xor(p, 2);
        p += __shfl_xor(p, 4);
        p += __shfl_xor(p, 8);
        if (l15 == 0) P_s[rb * 8 + w] = p;
    }
    __syncthreads();
    if (tid < BT2) {
        float s = 0.0f;
#pragma unroll
        for (int k = 0; k < 8; ++k) s += P_s[tid * 8 + k];
        out[b0 + tid] = 0.5f * (s - (float)DDIM);
    }
}

extern "C" void kernel_launch(void* const* d_in, const int* in_sizes, int n_in,
                              void* d_out, int out_size, void* d_ws, size_t ws_size,
                              hipStream_t stream) {
    const int*   x     = (const int*)  d_in[0];
    const int*   ctx   = (const int*)  d_in[1];
    const float* W_emb = (const float*)d_in[2];
    const float* M_w   = (const float*)d_in[3];
    const float* M_b   = (const float*)d_in[4];
    const float* U_w   = (const float*)d_in[5];
    const float* U_b   = (const float*)d_in[6];
    const float* W_w   = (const float*)d_in[7];
    const float* W_b   = (const float*)d_in[8];
    const float* pmu   = (const float*)d_in[9];
    const float* psg   = (const float*)d_in[10];
    float* out = (float*)d_out;
    unsigned short* ws = (unsigned short*)d_ws;   // needs >= 4,390,912 bytes

    k_cvt<<<dim3(96), dim3(256), 0, stream>>>(M_w, U_w, W_w, ws);
    bsg_h<<<dim3(8192 / BT1), dim3(512), 0, stream>>>(x, ctx, W_emb, M_b,
                                                      ws, ws + WS_H);
    bsg_kl<<<dim3(8192 / BT2), dim3(512), 0, stream>>>(x, U_b, W_b, pmu, psg,
                                                       ws, out);
}

// Round 14
// 42.043 us; speedup vs baseline: 1.0164x; 1.0164x over previous
//
#include <hip/hip_runtime.h>
#include <hip/hip_bf16.h>
#include <math.h>

// BayesianSkipgram: V=100000, E=256, D=128, B=8192, C=10
// v14 = v12 with intra-block 2-tile pipelined bsg_h:
//   block handles 2 tiles of 8 batch elems (grid 512). tile1's 11 gather
//   loads are issued right after tile0's staging barrier -> in flight
//   during tile0's MFMA. One LDS buffer reused (extra barrier). Both
//   relu-sum epilogues at the end so no vmcnt(0) drain catches h-stores.
//   bsg_kl, k_cvt: unchanged from v12.
// ws layout (ushort): M_bf [0,32768), U|W_bf [32768,98304), h [98304,+2M).

#define CTXN  10
#define DDIM  128
#define WS_M   0
#define WS_UW  32768
#define WS_H   98304

typedef short bf16x8 __attribute__((ext_vector_type(8)));
typedef float f32x4  __attribute__((ext_vector_type(4)));

__device__ __forceinline__ uint2 cvt4(float4 v) {
    union { __hip_bfloat162 h2; unsigned u; } a, b;
    a.h2 = __float22bfloat162_rn(make_float2(v.x, v.y));
    b.h2 = __float22bfloat162_rn(make_float2(v.z, v.w));
    return make_uint2(a.u, b.u);
}

__device__ __forceinline__ float softplusf(float v) {
    return fmaxf(v, 0.0f) + log1pf(expf(-fabsf(v)));
}

// ---------------- kernel 0: weight fp32 -> bf16 ----------------
__global__ __launch_bounds__(256) void k_cvt(
    const float* __restrict__ M_w, const float* __restrict__ U_w,
    const float* __restrict__ W_w, unsigned short* __restrict__ ws)
{
    int which = blockIdx.x >> 5;                       // 0:M 1:U 2:W
    int i = ((blockIdx.x & 31) << 8) | threadIdx.x;    // float4 idx 0..8191
    const float* src = (which == 0) ? M_w : (which == 1) ? U_w : W_w;
    float4 v = ((const float4*)src)[i];
    *(uint2*)&ws[which * 32768 + i * 4] = cvt4(v);
}

// ---------------- kernel 1: gather + emb@M_w^T + relu-sum -> h ----------------
#define BT1   16              // 2 tiles of 8 per block
#define LP2   264             // A row stride (ushort): 528 B -> 2-way bank alias (free)

__global__ __launch_bounds__(512, 4) void bsg_h(
    const int* __restrict__ x, const int* __restrict__ ctx,
    const float* __restrict__ W_emb, const float* __restrict__ M_b,
    const unsigned short* __restrict__ wsr, unsigned short* __restrict__ hws)
{
    __shared__ __align__(16) unsigned short A_s[96 * LP2];   // 50688 B
    __shared__ int idx_s[192];                               // [tile][96]

    const int tid  = threadIdx.x;
    const int b0   = blockIdx.x * BT1;
    const int w    = tid >> 6;       // wave 0..7 owns d-cols 16w..16w+15
    const int lane = tid & 63;
    const int l15  = lane & 15;
    const int lg   = lane >> 4;

    if (tid < 192) {                 // idx for both tiles; r = c*8+b per tile
        int t = (tid >= 96) ? 1 : 0;
        int u = tid - 96 * t;
        int c = u >> 3, b = b0 + 8 * t + (u & 7);
        idx_s[tid] = (c >= 11) ? 0 : ((c == 0) ? x[b] : ctx[b * CTXN + (c - 1)]);
    }
    __syncthreads();

    // staging geometry: wave rs stages all 11 slots of elem rs (rows c*8+rs)
    const int rs = tid >> 6;
    const int qs = tid & 63;
    const float4* We = (const float4*)W_emb;
    float4 rr[11];

    // ---- tile 0: load + stage ----
#pragma unroll
    for (int c = 0; c < 11; ++c) rr[c] = We[(size_t)idx_s[8 * c + rs] * 64 + qs];
#pragma unroll
    for (int c = 0; c < 11; ++c)
        *(uint2*)&A_s[(8 * c + rs) * LP2 + 4 * qs] = cvt4(rr[c]);
    __syncthreads();   // t0 staged (vmcnt(0): only t0 loads outstanding)

    // ---- tile 1 loads: issue NOW, in flight during MFMA(t0) ----
#pragma unroll
    for (int c = 0; c < 11; ++c) rr[c] = We[(size_t)idx_s[96 + 8 * c + rs] * 64 + qs];

    // ---- MFMA tile 0 ----
    const unsigned short* Mb_bf = wsr + WS_M;   // [128][256] bf16
    const int mrow = 16 * w + l15;
    f32x4 acc0[6] = {}, acc1[6] = {};
#pragma unroll
    for (int ch = 0; ch < 4; ++ch) {
        bf16x8 m0 = *(const bf16x8*)&Mb_bf[mrow * 256 + 64 * ch + 8 * lg];
        bf16x8 m1 = *(const bf16x8*)&Mb_bf[mrow * 256 + 64 * ch + 32 + 8 * lg];
#pragma unroll
        for (int mt = 0; mt < 6; ++mt) {
            bf16x8 a0 = *(const bf16x8*)&A_s[(16 * mt + l15) * LP2 + 64 * ch + 8 * lg];
            bf16x8 a1 = *(const bf16x8*)&A_s[(16 * mt + l15) * LP2 + 64 * ch + 32 + 8 * lg];
            acc0[mt] = __builtin_amdgcn_mfma_f32_16x16x32_bf16(a0, m0, acc0[mt], 0, 0, 0);
            acc0[mt] = __builtin_amdgcn_mfma_f32_16x16x32_bf16(a1, m1, acc0[mt], 0, 0, 0);
        }
    }
    __syncthreads();   // A_s reads done; t1 loads drained (needed for writes anyway)

    // ---- tile 1: stage + MFMA ----
#pragma unroll
    for (int c = 0; c < 11; ++c)
        *(uint2*)&A_s[(8 * c + rs) * LP2 + 4 * qs] = cvt4(rr[c]);
    __syncthreads();   // t1 staged (vmcnt already 0 -> only lgkm wait here)

#pragma unroll
    for (int ch = 0; ch < 4; ++ch) {
        bf16x8 m0 = *(const bf16x8*)&Mb_bf[mrow * 256 + 64 * ch + 8 * lg];
        bf16x8 m1 = *(const bf16x8*)&Mb_bf[mrow * 256 + 64 * ch + 32 + 8 * lg];
#pragma unroll
        for (int mt = 0; mt < 6; ++mt) {
            bf16x8 a0 = *(const bf16x8*)&A_s[(16 * mt + l15) * LP2 + 64 * ch + 8 * lg];
            bf16x8 a1 = *(const bf16x8*)&A_s[(16 * mt + l15) * LP2 + 64 * ch + 32 + 8 * lg];
            acc1[mt] = __builtin_amdgcn_mfma_f32_16x16x32_bf16(a0, m0, acc1[mt], 0, 0, 0);
            acc1[mt] = __builtin_amdgcn_mfma_f32_16x16x32_bf16(a1, m1, acc1[mt], 0, 0, 0);
        }
    }

    // ---- relu-sum epilogues, both tiles (no barriers after this point) ----
    // lane row = 16mt+4lg+q; c = row>>3, b = row&7.
    // lg<2 -> even slots (c=2mt), lg>=2 -> odd slots (c=2mt+1; mt=5 -> garbage, excluded).
    const int dg = 16 * w + l15;
    const float mb = M_b[dg];
#pragma unroll
    for (int t = 0; t < 2; ++t) {
        const f32x4* acc = t ? acc1 : acc0;
        float p1[4] = {0, 0, 0, 0}, p2[4] = {0, 0, 0, 0};
#pragma unroll
        for (int mt = 0; mt < 6; ++mt) {
#pragma unroll
            for (int q = 0; q < 4; ++q) {
                float r = fmaxf(acc[mt][q] + mb, 0.0f);
                if (lg < 2) { if (mt == 0) p1[q] = r; else p2[q] += r; }
                else        { if (mt < 5)  p2[q] += r; }
            }
        }
#pragma unroll
        for (int q = 0; q < 4; ++q) {
            float other = __shfl_xor(p2[q], 32);     // pair lg0<->lg2, lg1<->lg3
            if (lg < 2) {
                int b = 8 * t + 4 * lg + q;
                __hip_bfloat16 t1 = __float2bfloat16(10.0f * p1[q]);   // C*relu(Rw)
                __hip_bfloat16 t2 = __float2bfloat16(p2[q] + other);   // sum relu(Rc)
                hws[(size_t)(b0 + b) * 256 + dg]       = *(unsigned short*)&t1;
                hws[(size_t)(b0 + b) * 256 + 128 + dg] = *(unsigned short*)&t2;
            }
        }
    }
}

// ---------------- kernel 2: h @ [U;W]^T + softplus + KL ----------------
#define BT2  16
#define HLP  264

__global__ __launch_bounds__(512, 4) void bsg_kl(
    const int* __restrict__ x, const float* __restrict__ U_b,
    const float* __restrict__ W_b, const float* __restrict__ pmu,
    const float* __restrict__ psg, const unsigned short* __restrict__ wsr,
    float* __restrict__ out)
{
    __shared__ __align__(16) unsigned short H_s[BT2 * HLP];   // 8448 B
    __shared__ float P_s[BT2 * 8];

    const int tid  = threadIdx.x;
    const int b0   = blockIdx.x * BT2;
    const int w    = tid >> 6;       // wave 0..7 owns d-cols 16w..16w+15
    const int lane = tid & 63;
    const int l15  = lane & 15;
    const int lg   = lane >> 4;
    const int d    = 16 * w + l15;

    // prior gathers issued upfront (x[] L2-hot); consumed only in epilogue
    float pm[4], ps[4];
#pragma unroll
    for (int q = 0; q < 4; ++q) {
        int xb = x[b0 + 4 * lg + q];
        pm[q] = pmu[(size_t)xb * DDIM + d];
        ps[q] = psg[(size_t)xb * DDIM + d];
    }

    // h tile copy: 512 threads x 16B = whole [16][256] tile
    const unsigned short* hws = wsr + WS_H;
    {
        int r = tid >> 5, q = tid & 31;
        *(uint4*)&H_s[r * HLP + 8 * q] =
            *(const uint4*)&hws[(size_t)(b0 + r) * 256 + 8 * q];
    }
    __syncthreads();

    const unsigned short* UWb = wsr + WS_UW;    // [256][256]: 0..127=U, 128..255=W
    f32x4 acc2[2] = {};
#pragma unroll
    for (int ks = 0; ks < 8; ++ks) {
        bf16x8 hf = *(const bf16x8*)&H_s[l15 * HLP + 32 * ks + 8 * lg];
        bf16x8 bu = *(const bf16x8*)&UWb[d * 256 + 32 * ks + 8 * lg];
        bf16x8 bw = *(const bf16x8*)&UWb[(128 + d) * 256 + 32 * ks + 8 * lg];
        acc2[0] = __builtin_amdgcn_mfma_f32_16x16x32_bf16(hf, bu, acc2[0], 0, 0, 0);
        acc2[1] = __builtin_amdgcn_mfma_f32_16x16x32_bf16(hf, bw, acc2[1], 0, 0, 0);
    }

    const float ub = U_b[d], wb = W_b[d];
#pragma unroll
    for (int q = 0; q < 4; ++q) {
        int rb = 4 * lg + q;                    // batch row (C/D: row=4lg+q, col=l15)
        float mu = acc2[0][q] + ub;
        float sg = softplusf(acc2[1][q] + wb);
        float dm = mu - pm[q];
        float p  = ps[q] / sg + dm * dm / sg + logf(sg) - logf(ps[q]);
        p += __shfl_xor(p, 1);
        p += __shfl_xor(p, 2);
        p += __shfl_xor(p, 4);
        p += __shfl_xor(p, 8);
        if (l15 == 0) P_s[rb * 8 + w] = p;
    }
    __syncthreads();
    if (tid < BT2) {
        float s = 0.0f;
#pragma unroll
        for (int k = 0; k < 8; ++k) s += P_s[tid * 8 + k];
        out[b0 + tid] = 0.5f * (s - (float)DDIM);
    }
}

extern "C" void kernel_launch(void* const* d_in, const int* in_sizes, int n_in,
                              void* d_out, int out_size, void* d_ws, size_t ws_size,
                              hipStream_t stream) {
    const int*   x     = (const int*)  d_in[0];
    const int*   ctx   = (const int*)  d_in[1];
    const float* W_emb = (const float*)d_in[2];
    const float* M_w   = (const float*)d_in[3];
    const float* M_b   = (const float*)d_in[4];
    const float* U_w   = (const float*)d_in[5];
    const float* U_b   = (const float*)d_in[6];
    const float* W_w   = (const float*)d_in[7];
    const float* W_b   = (const float*)d_in[8];
    const float* pmu   = (const float*)d_in[9];
    const float* psg   = (const float*)d_in[10];
    float* out = (float*)d_out;
    unsigned short* ws = (unsigned short*)d_ws;   // needs >= 4,390,912 bytes

    k_cvt<<<dim3(96), dim3(256), 0, stream>>>(M_w, U_w, W_w, ws);
    bsg_h<<<dim3(8192 / BT1), dim3(512), 0, stream>>>(x, ctx, W_emb, M_b,
                                                      ws, ws + WS_H);
    bsg_kl<<<dim3(8192 / BT2), dim3(512), 0, stream>>>(x, U_b, W_b, pmu, psg,
                                                       ws, out);
}

// Round 15
// 41.495 us; speedup vs baseline: 1.0298x; 1.0132x over previous
//
#include <hip/hip_runtime.h>
#include <hip/hip_bf16.h>
#include <math.h>

// BayesianSkipgram: V=100000, E=256, D=128, B=8192, C=10
// v15 = v12 with bsg_kl at BT2=32 (halved UW panel traffic; v4-proven
//       2-M-tile-per-wave layout, priors hoisted).
//   bsg_h : v12's one-shot staging (12 wave-coalesced 1KB-row loads,
//           ONE barrier), unchanged.
//   k_cvt : unchanged.
// ws layout (ushort): M_bf [0,32768), U|W_bf [32768,98304), h [98304,+2M).

#define CTXN  10
#define DDIM  128
#define WS_M   0
#define WS_UW  32768
#define WS_H   98304

typedef short bf16x8 __attribute__((ext_vector_type(8)));
typedef float f32x4  __attribute__((ext_vector_type(4)));

__device__ __forceinline__ uint2 cvt4(float4 v) {
    union { __hip_bfloat162 h2; unsigned u; } a, b;
    a.h2 = __float22bfloat162_rn(make_float2(v.x, v.y));
    b.h2 = __float22bfloat162_rn(make_float2(v.z, v.w));
    return make_uint2(a.u, b.u);
}

__device__ __forceinline__ float softplusf(float v) {
    return fmaxf(v, 0.0f) + log1pf(expf(-fabsf(v)));
}

// ---------------- kernel 0: weight fp32 -> bf16 ----------------
__global__ __launch_bounds__(256) void k_cvt(
    const float* __restrict__ M_w, const float* __restrict__ U_w,
    const float* __restrict__ W_w, unsigned short* __restrict__ ws)
{
    int which = blockIdx.x >> 5;                       // 0:M 1:U 2:W
    int i = ((blockIdx.x & 31) << 8) | threadIdx.x;    // float4 idx 0..8191
    const float* src = (which == 0) ? M_w : (which == 1) ? U_w : W_w;
    float4 v = ((const float4*)src)[i];
    *(uint2*)&ws[which * 32768 + i * 4] = cvt4(v);
}

// ---------------- kernel 1: gather + emb@M_w^T + relu-sum -> h ----------------
#define BT1   8
#define ROWSP 96              // LDS rows 0..87 staged (r = c*8+b); 88..95 garbage
#define LP2   264             // A row stride (ushort): 528 B -> 2-way bank alias (free)

__global__ __launch_bounds__(512, 4) void bsg_h(
    const int* __restrict__ x, const int* __restrict__ ctx,
    const float* __restrict__ W_emb, const float* __restrict__ M_b,
    const unsigned short* __restrict__ wsr, unsigned short* __restrict__ hws)
{
    __shared__ __align__(16) unsigned short A_s[ROWSP * LP2];   // 50688 B
    __shared__ int idx_s[ROWSP];

    const int tid  = threadIdx.x;
    const int b0   = blockIdx.x * BT1;
    const int w    = tid >> 6;       // wave 0..7 owns d-cols 16w..16w+15
    const int lane = tid & 63;
    const int l15  = lane & 15;
    const int lg   = lane >> 4;

    if (tid < ROWSP) {
        int c = tid >> 3, b = b0 + (tid & 7);
        idx_s[tid] = (c >= 11) ? 0 : ((c == 0) ? x[b] : ctx[b * CTXN + (c - 1)]);
    }
    __syncthreads();

    // ---- single-shot staging: 12 steps, wave-per-row perfect coalescing ----
    const int rs = tid >> 6;
    const int qs = tid & 63;
    const float4* We = (const float4*)W_emb;

    float4 rr[12];
#pragma unroll
    for (int s = 0; s < 12; ++s)
        rr[s] = We[(size_t)idx_s[rs + 8 * s] * 64 + qs];
#pragma unroll
    for (int s = 0; s < 12; ++s)
        *(uint2*)&A_s[(rs + 8 * s) * LP2 + 4 * qs] = cvt4(rr[s]);
    __syncthreads();   // the only phase-1 barrier

    // ---- MFMA: 4 k-chunks x 6 M-tiles, M-frags from L2-hot bf16 ws ----
    const unsigned short* Mb_bf = wsr + WS_M;   // [128][256] bf16
    const int mrow = 16 * w + l15;
    f32x4 acc[6] = {};
#pragma unroll
    for (int ch = 0; ch < 4; ++ch) {
        bf16x8 m0 = *(const bf16x8*)&Mb_bf[mrow * 256 + 64 * ch + 8 * lg];
        bf16x8 m1 = *(const bf16x8*)&Mb_bf[mrow * 256 + 64 * ch + 32 + 8 * lg];
#pragma unroll
        for (int mt = 0; mt < 6; ++mt) {
            bf16x8 a0 = *(const bf16x8*)&A_s[(16 * mt + l15) * LP2 + 64 * ch + 8 * lg];
            bf16x8 a1 = *(const bf16x8*)&A_s[(16 * mt + l15) * LP2 + 64 * ch + 32 + 8 * lg];
            acc[mt] = __builtin_amdgcn_mfma_f32_16x16x32_bf16(a0, m0, acc[mt], 0, 0, 0);
            acc[mt] = __builtin_amdgcn_mfma_f32_16x16x32_bf16(a1, m1, acc[mt], 0, 0, 0);
        }
    }

    // relu-sum: lane row = 16mt+4lg+q; c = row>>3, b = row&7.
    // lg<2 -> even slots (c=2mt), lg>=2 -> odd slots (c=2mt+1; mt=5 -> pad).
    const int dg = 16 * w + l15;
    const float mb = M_b[dg];
    float p1[4] = {0, 0, 0, 0}, p2[4] = {0, 0, 0, 0};
#pragma unroll
    for (int mt = 0; mt < 6; ++mt) {
#pragma unroll
        for (int q = 0; q < 4; ++q) {
            float r = fmaxf(acc[mt][q] + mb, 0.0f);
            if (lg < 2) { if (mt == 0) p1[q] = r; else p2[q] += r; }
            else        { if (mt < 5)  p2[q] += r; }
        }
    }
#pragma unroll
    for (int q = 0; q < 4; ++q) {
        float other = __shfl_xor(p2[q], 32);     // pair lg0<->lg2, lg1<->lg3
        if (lg < 2) {
            int b = 4 * lg + q;
            __hip_bfloat16 t1 = __float2bfloat16(10.0f * p1[q]);   // C*relu(Rw)
            __hip_bfloat16 t2 = __float2bfloat16(p2[q] + other);   // sum relu(Rc)
            hws[(size_t)(b0 + b) * 256 + dg]       = *(unsigned short*)&t1;
            hws[(size_t)(b0 + b) * 256 + 128 + dg] = *(unsigned short*)&t2;
        }
    }
}

// ---------------- kernel 2: h @ [U;W]^T + softplus + KL (BT2=32) ----------------
#define BT2  32
#define HLP  264

__global__ __launch_bounds__(512, 4) void bsg_kl(
    const int* __restrict__ x, const float* __restrict__ U_b,
    const float* __restrict__ W_b, const float* __restrict__ pmu,
    const float* __restrict__ psg, const unsigned short* __restrict__ wsr,
    float* __restrict__ out)
{
    __shared__ __align__(16) unsigned short H_s[BT2 * HLP];   // 16896 B
    __shared__ float P_s[BT2 * 8];

    const int tid  = threadIdx.x;
    const int b0   = blockIdx.x * BT2;
    const int w    = tid >> 6;       // wave 0..7 owns d-cols 16w..16w+15
    const int lane = tid & 63;
    const int l15  = lane & 15;
    const int lg   = lane >> 4;
    const int d    = 16 * w + l15;

    // prior gathers issued upfront (x[] L2-hot); consumed only in epilogue
    float pm[2][4], ps[2][4];
#pragma unroll
    for (int mt = 0; mt < 2; ++mt)
#pragma unroll
        for (int q = 0; q < 4; ++q) {
            int xb = x[b0 + 16 * mt + 4 * lg + q];
            pm[mt][q] = pmu[(size_t)xb * DDIM + d];
            ps[mt][q] = psg[(size_t)xb * DDIM + d];
        }

    // h tile copy: 512 threads x 2 x 16B = whole [32][256] tile
    const unsigned short* hws = wsr + WS_H;
#pragma unroll
    for (int s = 0; s < 2; ++s) {
        int it = tid + 512 * s;
        int r = it >> 5, q = it & 31;
        *(uint4*)&H_s[r * HLP + 8 * q] =
            *(const uint4*)&hws[(size_t)(b0 + r) * 256 + 8 * q];
    }
    __syncthreads();

    const unsigned short* UWb = wsr + WS_UW;    // [256][256]: 0..127=U, 128..255=W
    f32x4 acc2[2][2] = {};                      // [mtile][0=mu,1=presig]
#pragma unroll
    for (int ks = 0; ks < 8; ++ks) {
        bf16x8 bu = *(const bf16x8*)&UWb[d * 256 + 32 * ks + 8 * lg];
        bf16x8 bw = *(const bf16x8*)&UWb[(128 + d) * 256 + 32 * ks + 8 * lg];
#pragma unroll
        for (int mt = 0; mt < 2; ++mt) {
            bf16x8 hf = *(const bf16x8*)&H_s[(16 * mt + l15) * HLP + 32 * ks + 8 * lg];
            acc2[mt][0] = __builtin_amdgcn_mfma_f32_16x16x32_bf16(hf, bu, acc2[mt][0], 0, 0, 0);
            acc2[mt][1] = __builtin_amdgcn_mfma_f32_16x16x32_bf16(hf, bw, acc2[mt][1], 0, 0, 0);
        }
    }

    const float ub = U_b[d], wb = W_b[d];
#pragma unroll
    for (int mt = 0; mt < 2; ++mt) {
#pragma unroll
        for (int q = 0; q < 4; ++q) {
            int rb = 16 * mt + 4 * lg + q;      // batch row (C/D: row=4lg+q, col=l15)
            float mu = acc2[mt][0][q] + ub;
            float sg = softplusf(acc2[mt][1][q] + wb);
            float dm = mu - pm[mt][q];
            float p  = ps[mt][q] / sg + dm * dm / sg + logf(sg) - logf(ps[mt][q]);
            p += __shfl_xor(p, 1);
            p += __shfl_xor(p, 2);
            p += __shfl_xor(p, 4);
            p += __shfl_xor(p, 8);
            if (l15 == 0) P_s[rb * 8 + w] = p;
        }
    }
    __syncthreads();
    if (tid < BT2) {
        float s = 0.0f;
#pragma unroll
        for (int k = 0; k < 8; ++k) s += P_s[tid * 8 + k];
        out[b0 + tid] = 0.5f * (s - (float)DDIM);
    }
}

extern "C" void kernel_launch(void* const* d_in, const int* in_sizes, int n_in,
                              void* d_out, int out_size, void* d_ws, size_t ws_size,
                              hipStream_t stream) {
    const int*   x     = (const int*)  d_in[0];
    const int*   ctx   = (const int*)  d_in[1];
    const float* W_emb = (const float*)d_in[2];
    const float* M_w   = (const float*)d_in[3];
    const float* M_b   = (const float*)d_in[4];
    const float* U_w   = (const float*)d_in[5];
    const float* U_b   = (const float*)d_in[6];
    const float* W_w   = (const float*)d_in[7];
    const float* W_b   = (const float*)d_in[8];
    const float* pmu   = (const float*)d_in[9];
    const float* psg   = (const float*)d_in[10];
    float* out = (float*)d_out;
    unsigned short* ws = (unsigned short*)d_ws;   // needs >= 4,390,912 bytes

    k_cvt<<<dim3(96), dim3(256), 0, stream>>>(M_w, U_w, W_w, ws);
    bsg_h<<<dim3(8192 / BT1), dim3(512), 0, stream>>>(x, ctx, W_emb, M_b,
                                                      ws, ws + WS_H);
    bsg_kl<<<dim3(8192 / BT2), dim3(512), 0, stream>>>(x, U_b, W_b, pmu, psg,
                                                       ws, out);
}